// Round 2
// baseline (347.740 us; speedup 1.0000x reference)
//
#include <hip/hip_runtime.h>

#define NN 50000
#define NE 800000
#define NF 128
#define DIM 32
#define NG 500

// ---------- k1: y = x@w_rel ; root = x@w_root + b_rel ----------
__global__ __launch_bounds__(256) void proj_kernel(
    const float* __restrict__ x, const float* __restrict__ w_rel,
    const float* __restrict__ w_root, const float* __restrict__ b_rel,
    float* __restrict__ y, float* __restrict__ root)
{
    __shared__ float s_w[2 * NF * DIM];   // 32 KB: [0..4095]=w_rel, [4096..]=w_root
    __shared__ float s_x[32 * NF];        // 16 KB: 32 rows of x
    int tid = threadIdx.x;
#pragma unroll
    for (int j = 0; j < 16; ++j) {
        s_w[tid + j * 256]        = w_rel[tid + j * 256];
        s_w[4096 + tid + j * 256] = w_root[tid + j * 256];
    }
    int rb = blockIdx.x * 32;
#pragma unroll
    for (int j = 0; j < 16; ++j) {
        int idx = rb * NF + tid + j * 256;
        s_x[tid + j * 256] = (idx < NN * NF) ? x[idx] : 0.0f;
    }
    __syncthreads();

    int col = tid & 31;
    int sel = (tid >> 5) & 1;      // 0 -> y (w_rel, no bias), 1 -> root (w_root + b_rel)
    int r0  = (tid >> 6) * 8;      // 8 rows per thread
    const float* W = s_w + sel * 4096;
    float bias = sel ? b_rel[col] : 0.0f;
    float acc[8];
#pragma unroll
    for (int j = 0; j < 8; ++j) acc[j] = bias;
    const float* xr = s_x + r0 * NF;
#pragma unroll 4
    for (int k = 0; k < NF; ++k) {
        float wv = W[k * DIM + col];          // 2-way bank alias (free)
#pragma unroll
        for (int j = 0; j < 8; ++j)
            acc[j] = fmaf(xr[j * NF + k], wv, acc[j]);  // wave-uniform broadcast
    }
    float* dst = sel ? root : y;
#pragma unroll
    for (int j = 0; j < 8; ++j) {
        int row = rb + r0 + j;
        if (row < NN) dst[row * DIM + col] = acc[j];
    }
}

// ---------- k2: degree histogram by dst + graph boundary offsets ----------
__global__ __launch_bounds__(256) void hist_kernel(
    const int* __restrict__ ei, const int* __restrict__ batch,
    int* __restrict__ hist, int* __restrict__ gb)
{
    int gtid = blockIdx.x * 256 + threadIdx.x;
    if (gtid < NE) atomicAdd(&hist[ei[NE + gtid]], 1);
    if (gtid < NN) {
        int bi = batch[gtid];
        int bp = (gtid == 0) ? -1 : batch[gtid - 1];
        for (int g = bp + 1; g <= bi; ++g) gb[g] = gtid;
        if (gtid == NN - 1)
            for (int g = bi + 1; g <= NG; ++g) gb[g] = NN;
    }
}

// ---------- k3: exclusive scan of hist -> csr_off, cursor ----------
#define CHUNK 49
__global__ __launch_bounds__(1024) void scan_kernel(
    const int* __restrict__ hist, int* __restrict__ csr_off, int* __restrict__ cursor)
{
    __shared__ int s_sum[1024];
    int t = threadIdx.x;
    int b0 = t * CHUNK;
    int sum = 0;
    for (int j = 0; j < CHUNK; ++j) {
        int b = b0 + j;
        if (b < NN) sum += hist[b];
    }
    s_sum[t] = sum;
    __syncthreads();
    for (int ofs = 1; ofs < 1024; ofs <<= 1) {
        int v = (t >= ofs) ? s_sum[t - ofs] : 0;
        __syncthreads();
        s_sum[t] += v;
        __syncthreads();
    }
    int base = s_sum[t] - sum;   // exclusive prefix
    for (int j = 0; j < CHUNK; ++j) {
        int b = b0 + j;
        if (b < NN) {
            int v = hist[b];
            csr_off[b] = base;
            cursor[b]  = base;
            base += v;
        }
    }
    if (t == 0) csr_off[NN] = NE;
}

// ---------- k4: scatter edges into CSR buckets ----------
__global__ __launch_bounds__(256) void scatter_kernel(
    const int* __restrict__ ei, const float* __restrict__ ew,
    int* __restrict__ cursor, uint2* __restrict__ srcw)
{
    int e = blockIdx.x * 256 + threadIdx.x;
    if (e >= NE) return;
    int s = ei[e], d = ei[NE + e];
    float w = ew[e];
    int pos = atomicAdd(&cursor[d], 1);
    srcw[pos] = make_uint2((unsigned)s, __float_as_uint(w));
}

// ---------- k5: per-graph gather-aggregate + relu + pool (no atomics) ----------
__global__ __launch_bounds__(512) void aggpool_kernel(
    const float* __restrict__ y, const float* __restrict__ root,
    const int* __restrict__ csr_off, const uint2* __restrict__ srcw,
    const int* __restrict__ gb, float* __restrict__ pooled)
{
    __shared__ float s_p[512];
    int g = blockIdx.x;
    int tid = threadIdx.x;
    int slot = tid >> 5, c = tid & 31;   // 16 node-slots x 32 cols
    int n0 = gb[g], n1 = gb[g + 1];
    float p = 0.0f;
    for (int i = n0 + slot; i < n1; i += 16) {
        float val = root[i * DIM + c];
        int e0 = csr_off[i], e1 = csr_off[i + 1];
        for (int e = e0; e < e1; ++e) {
            uint2 pk = srcw[e];                       // broadcast within group
            val = fmaf(__uint_as_float(pk.y), y[pk.x * DIM + c], val);
        }
        p += fmaxf(val, 0.0f);
    }
    s_p[tid] = p;
    __syncthreads();
    if (tid < 256) s_p[tid] += s_p[tid + 256];
    __syncthreads();
    if (tid < 128) s_p[tid] += s_p[tid + 128];
    __syncthreads();
    if (tid < 64)  s_p[tid] += s_p[tid + 64];
    __syncthreads();
    if (tid < 32)  pooled[g * DIM + tid] = s_p[tid] + s_p[tid + 32];
}

// ---------- k6: MLP head + log_softmax ----------
__global__ __launch_bounds__(512) void head_kernel(
    const float* __restrict__ pooled, const float* __restrict__ w_fc1,
    const float* __restrict__ b_fc1, const float* __restrict__ w_fc2,
    const float* __restrict__ b_fc2, float* __restrict__ out)
{
    __shared__ float s_fc1[DIM * DIM];
    __shared__ float s_b1[DIM];
    __shared__ float s_fc2[DIM * 2];
    __shared__ float s_b2[2];
    int tid = threadIdx.x;
    s_fc1[tid]       = w_fc1[tid];
    s_fc1[tid + 512] = w_fc1[tid + 512];
    if (tid < DIM * 2) s_fc2[tid] = w_fc2[tid];
    if (tid < DIM)     s_b1[tid]  = b_fc1[tid];
    if (tid < 2)       s_b2[tid]  = b_fc2[tid];
    __syncthreads();

    int g = tid;
    if (g >= NG) return;
    const float* p = pooled + g * DIM;
    float h2[DIM];
#pragma unroll
    for (int c = 0; c < DIM; ++c) {
        float a = s_b1[c];
#pragma unroll
        for (int k = 0; k < DIM; ++k)
            a = fmaf(p[k], s_fc1[k * DIM + c], a);
        h2[c] = a > 0.0f ? a : 0.0f;
    }
    float l0 = s_b2[0], l1 = s_b2[1];
#pragma unroll
    for (int c = 0; c < DIM; ++c) {
        l0 = fmaf(h2[c], s_fc2[c * 2 + 0], l0);
        l1 = fmaf(h2[c], s_fc2[c * 2 + 1], l1);
    }
    float m   = fmaxf(l0, l1);
    float lse = m + logf(expf(l0 - m) + expf(l1 - m));
    out[g * 2 + 0] = l0 - lse;
    out[g * 2 + 1] = l1 - lse;
}

extern "C" void kernel_launch(void* const* d_in, const int* in_sizes, int n_in,
                              void* d_out, int out_size, void* d_ws, size_t ws_size,
                              hipStream_t stream) {
    const float* x      = (const float*)d_in[0];
    const float* ew     = (const float*)d_in[1];
    const float* w_rel  = (const float*)d_in[2];
    const float* b_rel  = (const float*)d_in[3];
    const float* w_root = (const float*)d_in[4];
    const float* w_fc1  = (const float*)d_in[5];
    const float* b_fc1  = (const float*)d_in[6];
    const float* w_fc2  = (const float*)d_in[7];
    const float* b_fc2  = (const float*)d_in[8];
    const int*   ei     = (const int*)d_in[9];
    const int*   batch  = (const int*)d_in[10];
    float* out = (float*)d_out;

    char* ws = (char*)d_ws;
    float* y       = (float*)ws;                              // 6.4 MB
    float* root    = y + (size_t)NN * DIM;                    // 6.4 MB
    uint2* srcw    = (uint2*)(root + (size_t)NN * DIM);       // 6.4 MB
    int*   csr_off = (int*)(srcw + NE);                       // NN+1
    int*   cursor  = csr_off + NN + 2;                        // NN
    int*   hist    = cursor + NN;                             // NN
    int*   gb      = hist + NN;                               // NG+1
    float* pooled  = (float*)(gb + NG + 2);                   // 64 KB

    hipMemsetAsync(hist, 0, NN * sizeof(int), stream);

    proj_kernel<<<(NN + 31) / 32, 256, 0, stream>>>(x, w_rel, w_root, b_rel, y, root);
    hist_kernel<<<(NE + 255) / 256, 256, 0, stream>>>(ei, batch, hist, gb);
    scan_kernel<<<1, 1024, 0, stream>>>(hist, csr_off, cursor);
    scatter_kernel<<<(NE + 255) / 256, 256, 0, stream>>>(ei, ew, cursor, srcw);
    aggpool_kernel<<<NG, 512, 0, stream>>>(y, root, csr_off, srcw, gb, pooled);
    head_kernel<<<1, 512, 0, stream>>>(pooled, w_fc1, b_fc1, w_fc2, b_fc2, out);
}

// Round 3
// 187.932 us; speedup vs baseline: 1.8503x; 1.8503x over previous
//
#include <hip/hip_runtime.h>

#define NN 50000
#define NE 800000
#define NF 128
#define DIM 32
#define NG 500
#define SCAN_B 196   // ceil(NN/256)
#define SPLIT 4      // blocks per graph in aggpool

// ---------- k1: y = x@w_rel ; root = x@w_root + b_rel ----------
__global__ __launch_bounds__(256) void proj_kernel(
    const float* __restrict__ x, const float* __restrict__ w_rel,
    const float* __restrict__ w_root, const float* __restrict__ b_rel,
    float* __restrict__ y, float* __restrict__ root)
{
    __shared__ float s_w[2 * NF * DIM];   // 32 KB
    __shared__ float s_x[32 * NF];        // 16 KB
    int tid = threadIdx.x;
#pragma unroll
    for (int j = 0; j < 16; ++j) {
        s_w[tid + j * 256]        = w_rel[tid + j * 256];
        s_w[4096 + tid + j * 256] = w_root[tid + j * 256];
    }
    int rb = blockIdx.x * 32;
#pragma unroll
    for (int j = 0; j < 16; ++j) {
        int idx = rb * NF + tid + j * 256;
        s_x[tid + j * 256] = (idx < NN * NF) ? x[idx] : 0.0f;
    }
    __syncthreads();

    int col = tid & 31;
    int sel = (tid >> 5) & 1;      // 0 -> y (w_rel), 1 -> root (w_root + b_rel)
    int r0  = (tid >> 6) * 8;      // 8 rows per thread (wave-uniform)
    const float* W = s_w + sel * 4096;
    float bias = sel ? b_rel[col] : 0.0f;
    float acc[8];
#pragma unroll
    for (int j = 0; j < 8; ++j) acc[j] = bias;
    const float* xr = s_x + r0 * NF;
#pragma unroll 8
    for (int k = 0; k < NF; k += 4) {
        float w0 = W[(k + 0) * DIM + col];
        float w1 = W[(k + 1) * DIM + col];
        float w2 = W[(k + 2) * DIM + col];
        float w3 = W[(k + 3) * DIM + col];
#pragma unroll
        for (int j = 0; j < 8; ++j) {
            float4 xv = *reinterpret_cast<const float4*>(&xr[j * NF + k]);  // broadcast b128
            acc[j] = fmaf(xv.x, w0, acc[j]);
            acc[j] = fmaf(xv.y, w1, acc[j]);
            acc[j] = fmaf(xv.z, w2, acc[j]);
            acc[j] = fmaf(xv.w, w3, acc[j]);
        }
    }
    float* dst = sel ? root : y;
#pragma unroll
    for (int j = 0; j < 8; ++j) {
        int row = rb + r0 + j;
        if (row < NN) dst[row * DIM + col] = acc[j];
    }
}

// ---------- k2: degree histogram by dst + graph boundary offsets ----------
__global__ __launch_bounds__(256) void hist_kernel(
    const int* __restrict__ ei, const int* __restrict__ batch,
    int* __restrict__ hist, int* __restrict__ gb)
{
    int gtid = blockIdx.x * 256 + threadIdx.x;
    if (gtid < NE) atomicAdd(&hist[ei[NE + gtid]], 1);
    if (gtid < NN) {
        int bi = batch[gtid];
        int bp = (gtid == 0) ? -1 : batch[gtid - 1];
        for (int g = bp + 1; g <= bi; ++g) gb[g] = gtid;
        if (gtid == NN - 1)
            for (int g = bi + 1; g <= NG; ++g) gb[g] = NN;
    }
}

// ---------- k3a: per-block sums of hist ----------
__global__ __launch_bounds__(256) void bsum_kernel(
    const int* __restrict__ hist, int* __restrict__ bsum)
{
    int i = blockIdx.x * 256 + threadIdx.x;
    int v = (i < NN) ? hist[i] : 0;
#pragma unroll
    for (int o = 32; o; o >>= 1) v += __shfl_down(v, o, 64);
    __shared__ int s[4];
    if ((threadIdx.x & 63) == 0) s[threadIdx.x >> 6] = v;
    __syncthreads();
    if (threadIdx.x == 0) bsum[blockIdx.x] = s[0] + s[1] + s[2] + s[3];
}

// ---------- k3b: exclusive scan of the 196 block sums ----------
__global__ __launch_bounds__(256) void bscan_kernel(
    const int* __restrict__ bsum, int* __restrict__ boff)
{
    __shared__ int s[256];
    int t = threadIdx.x;
    int v = (t < SCAN_B) ? bsum[t] : 0;
    s[t] = v;
    __syncthreads();
    for (int o = 1; o < 256; o <<= 1) {
        int u = (t >= o) ? s[t - o] : 0;
        __syncthreads();
        s[t] += u;
        __syncthreads();
    }
    if (t < SCAN_B) boff[t] = s[t] - v;
}

// ---------- k3c: per-block exclusive scan + global offset -> csr_off, cursor ----------
__global__ __launch_bounds__(256) void cscan_kernel(
    const int* __restrict__ hist, const int* __restrict__ boff,
    int* __restrict__ csr_off, int* __restrict__ cursor)
{
    __shared__ int s[256];
    int t = threadIdx.x, i = blockIdx.x * 256 + t;
    int v = (i < NN) ? hist[i] : 0;
    s[t] = v;
    __syncthreads();
    for (int o = 1; o < 256; o <<= 1) {
        int u = (t >= o) ? s[t - o] : 0;
        __syncthreads();
        s[t] += u;
        __syncthreads();
    }
    int off = boff[blockIdx.x] + s[t] - v;   // exclusive
    if (i < NN) { csr_off[i] = off; cursor[i] = off; }
    if (i == NN - 1) csr_off[NN] = NE;
}

// ---------- k4: scatter edges into CSR buckets ----------
__global__ __launch_bounds__(256) void scatter_kernel(
    const int* __restrict__ ei, const float* __restrict__ ew,
    int* __restrict__ cursor, uint2* __restrict__ srcw)
{
    int e = blockIdx.x * 256 + threadIdx.x;
    if (e >= NE) return;
    int s = ei[e], d = ei[NE + e];
    float w = ew[e];
    int pos = atomicAdd(&cursor[d], 1);
    srcw[pos] = make_uint2((unsigned)s, __float_as_uint(w));
}

// ---------- k5: gather-aggregate + relu + pool (4 blocks/graph) ----------
__global__ __launch_bounds__(256) void aggpool_kernel(
    const float* __restrict__ y, const float* __restrict__ root,
    const int* __restrict__ csr_off, const uint2* __restrict__ srcw,
    const int* __restrict__ gb, float* __restrict__ pooled)
{
    int g    = blockIdx.x >> 2;
    int part = blockIdx.x & (SPLIT - 1);
    int tid  = threadIdx.x;
    int slot = tid >> 5, c = tid & 31;        // 8 node-slots x 32 cols
    int n0 = gb[g], n1 = gb[g + 1];
    float p = 0.0f;
    for (int i = n0 + part * 8 + slot; i < n1; i += 32) {
        float val = root[i * DIM + c];
        int e0 = csr_off[i], e1 = csr_off[i + 1];
        int e = e0;
        for (; e + 4 <= e1; e += 4) {
            uint2 p0 = srcw[e],     p1 = srcw[e + 1];
            uint2 p2 = srcw[e + 2], p3 = srcw[e + 3];
            float v0 = y[p0.x * DIM + c], v1 = y[p1.x * DIM + c];
            float v2 = y[p2.x * DIM + c], v3 = y[p3.x * DIM + c];
            val = fmaf(__uint_as_float(p0.y), v0, val);
            val = fmaf(__uint_as_float(p1.y), v1, val);
            val = fmaf(__uint_as_float(p2.y), v2, val);
            val = fmaf(__uint_as_float(p3.y), v3, val);
        }
        for (; e < e1; ++e) {
            uint2 pk = srcw[e];
            val = fmaf(__uint_as_float(pk.y), y[pk.x * DIM + c], val);
        }
        p += fmaxf(val, 0.0f);
    }
    __shared__ float s_p[256];
    s_p[tid] = p;
    __syncthreads();
    if (tid < 128) s_p[tid] += s_p[tid + 128];
    __syncthreads();
    if (tid < 64)  s_p[tid] += s_p[tid + 64];
    __syncthreads();
    if (tid < 32)  atomicAdd(&pooled[g * DIM + tid], s_p[tid] + s_p[tid + 32]);
}

// ---------- k6: MLP head + log_softmax ----------
__global__ __launch_bounds__(512) void head_kernel(
    const float* __restrict__ pooled, const float* __restrict__ w_fc1,
    const float* __restrict__ b_fc1, const float* __restrict__ w_fc2,
    const float* __restrict__ b_fc2, float* __restrict__ out)
{
    __shared__ float s_fc1[DIM * DIM];
    __shared__ float s_b1[DIM];
    __shared__ float s_fc2[DIM * 2];
    __shared__ float s_b2[2];
    int tid = threadIdx.x;
    s_fc1[tid]       = w_fc1[tid];
    s_fc1[tid + 512] = w_fc1[tid + 512];
    if (tid < DIM * 2) s_fc2[tid] = w_fc2[tid];
    if (tid < DIM)     s_b1[tid]  = b_fc1[tid];
    if (tid < 2)       s_b2[tid]  = b_fc2[tid];
    __syncthreads();

    int g = tid;
    if (g >= NG) return;
    const float* p = pooled + g * DIM;
    float h2[DIM];
#pragma unroll
    for (int c = 0; c < DIM; ++c) {
        float a = s_b1[c];
#pragma unroll
        for (int k = 0; k < DIM; ++k)
            a = fmaf(p[k], s_fc1[k * DIM + c], a);
        h2[c] = a > 0.0f ? a : 0.0f;
    }
    float l0 = s_b2[0], l1 = s_b2[1];
#pragma unroll
    for (int c = 0; c < DIM; ++c) {
        l0 = fmaf(h2[c], s_fc2[c * 2 + 0], l0);
        l1 = fmaf(h2[c], s_fc2[c * 2 + 1], l1);
    }
    float m   = fmaxf(l0, l1);
    float lse = m + logf(expf(l0 - m) + expf(l1 - m));
    out[g * 2 + 0] = l0 - lse;
    out[g * 2 + 1] = l1 - lse;
}

extern "C" void kernel_launch(void* const* d_in, const int* in_sizes, int n_in,
                              void* d_out, int out_size, void* d_ws, size_t ws_size,
                              hipStream_t stream) {
    const float* x      = (const float*)d_in[0];
    const float* ew     = (const float*)d_in[1];
    const float* w_rel  = (const float*)d_in[2];
    const float* b_rel  = (const float*)d_in[3];
    const float* w_root = (const float*)d_in[4];
    const float* w_fc1  = (const float*)d_in[5];
    const float* b_fc1  = (const float*)d_in[6];
    const float* w_fc2  = (const float*)d_in[7];
    const float* b_fc2  = (const float*)d_in[8];
    const int*   ei     = (const int*)d_in[9];
    const int*   batch  = (const int*)d_in[10];
    float* out = (float*)d_out;

    char* ws = (char*)d_ws;
    float* y       = (float*)ws;                              // 6.4 MB
    float* root    = y + (size_t)NN * DIM;                    // 6.4 MB
    uint2* srcw    = (uint2*)(root + (size_t)NN * DIM);       // 6.4 MB
    int*   csr_off = (int*)(srcw + NE);                       // NN+1
    int*   cursor  = csr_off + NN + 2;                        // NN
    int*   hist    = cursor + NN;                             // NN
    int*   gb      = hist + NN;                               // NG+1
    int*   bsum    = gb + NG + 2;                             // SCAN_B
    int*   boff    = bsum + SCAN_B;                           // SCAN_B
    float* pooled  = (float*)(boff + SCAN_B);                 // 64 KB

    hipMemsetAsync(hist, 0, NN * sizeof(int), stream);
    hipMemsetAsync(pooled, 0, NG * DIM * sizeof(float), stream);

    proj_kernel<<<(NN + 31) / 32, 256, 0, stream>>>(x, w_rel, w_root, b_rel, y, root);
    hist_kernel<<<(NE + 255) / 256, 256, 0, stream>>>(ei, batch, hist, gb);
    bsum_kernel<<<SCAN_B, 256, 0, stream>>>(hist, bsum);
    bscan_kernel<<<1, 256, 0, stream>>>(bsum, boff);
    cscan_kernel<<<SCAN_B, 256, 0, stream>>>(hist, boff, csr_off, cursor);
    scatter_kernel<<<(NE + 255) / 256, 256, 0, stream>>>(ei, ew, cursor, srcw);
    aggpool_kernel<<<NG * SPLIT, 256, 0, stream>>>(y, root, csr_off, srcw, gb, pooled);
    head_kernel<<<1, 512, 0, stream>>>(pooled, w_fc1, b_fc1, w_fc2, b_fc2, out);
}